// Round 2
// baseline (759.902 us; speedup 1.0000x reference)
//
#include <hip/hip_runtime.h>
#include <hip/hip_bf16.h>

#define N_TOK 4096
#define H_DIM 2048
#define I_DIM 1408
#define E_NUM 8
#define CAP   1280

typedef __hip_bfloat16 bf16;
typedef unsigned short us;
typedef __bf16 bf16x8 __attribute__((ext_vector_type(8)));
typedef float f32x4 __attribute__((ext_vector_type(4)));

__device__ inline void gld_lds16(const void* g, void* l) {
    __builtin_amdgcn_global_load_lds((const __attribute__((address_space(1))) void*)g,
                                     (__attribute__((address_space(3))) void*)l,
                                     16, 0, 0);
}

// ---------------- fp32 -> bf16 conversion ----------------
__device__ inline void cvt_body(const float* __restrict__ s, us* __restrict__ d, long i, long n) {
    if (i >= n) return;
    float4 v = *(const float4*)(s + i);
    union { us u[4]; ushort2 h[2]; } o;
    bf16 b0 = __float2bfloat16(v.x);
    bf16 b1 = __float2bfloat16(v.y);
    bf16 b2 = __float2bfloat16(v.z);
    bf16 b3 = __float2bfloat16(v.w);
    o.u[0] = *(us*)&b0; o.u[1] = *(us*)&b1; o.u[2] = *(us*)&b2; o.u[3] = *(us*)&b3;
    *(ushort2*)(d + i)     = o.h[0];
    *(ushort2*)(d + i + 2) = o.h[1];
}

__global__ void cvt4(const float* __restrict__ s, us* __restrict__ d, long n) {
    long i = ((long)blockIdx.x * blockDim.x + threadIdx.x) * 4;
    cvt_body(s, d, i, n);
}

// one launch converts all three weight tensors (same element count), z selects
__global__ void cvt_w3(const float* __restrict__ s0, const float* __restrict__ s1,
                       const float* __restrict__ s2, us* __restrict__ d0,
                       us* __restrict__ d1, us* __restrict__ d2, long n) {
    long i = ((long)blockIdx.x * blockDim.x + threadIdx.x) * 4;
    const float* s = blockIdx.z == 0 ? s0 : (blockIdx.z == 1 ? s1 : s2);
    us* d = blockIdx.z == 0 ? d0 : (blockIdx.z == 1 ? d1 : d2);
    cvt_body(s, d, i, n);
}

// ---------------- router: logits -> softmax -> top2 ----------------
__global__ void router_k(const float* __restrict__ x, const float* __restrict__ Wr,
                         float* __restrict__ top_val, int* __restrict__ top_idx) {
    int tok  = (blockIdx.x * blockDim.x + threadIdx.x) >> 6;
    int lane = threadIdx.x & 63;
    if (tok >= N_TOK) return;
    const float* xr = x + (size_t)tok * H_DIM;
    float acc[E_NUM];
#pragma unroll
    for (int e = 0; e < E_NUM; e++) acc[e] = 0.f;
    for (int h = lane; h < H_DIM; h += 64) {
        float xv = xr[h];
#pragma unroll
        for (int e = 0; e < E_NUM; e++) acc[e] += xv * Wr[e * H_DIM + h];
    }
#pragma unroll
    for (int e = 0; e < E_NUM; e++) {
#pragma unroll
        for (int off = 32; off > 0; off >>= 1) acc[e] += __shfl_xor(acc[e], off, 64);
    }
    if (lane == 0) {
        float mx = acc[0];
#pragma unroll
        for (int e = 1; e < E_NUM; e++) mx = fmaxf(mx, acc[e]);
        float p[E_NUM], s = 0.f;
#pragma unroll
        for (int e = 0; e < E_NUM; e++) { p[e] = __expf(acc[e] - mx); s += p[e]; }
        float inv = 1.f / s;
#pragma unroll
        for (int e = 0; e < E_NUM; e++) p[e] *= inv;
        int i0 = 0;
#pragma unroll
        for (int e = 1; e < E_NUM; e++) if (p[e] > p[i0]) i0 = e;
        int i1 = -1;
#pragma unroll
        for (int e = 0; e < E_NUM; e++) {
            if (e == i0) continue;
            if (i1 < 0 || p[e] > p[i1]) i1 = e;
        }
        top_idx[tok * 2]     = i0;
        top_idx[tok * 2 + 1] = i1;
        top_val[tok * 2]     = p[i0];
        top_val[tok * 2 + 1] = p[i1];
    }
}

// ---------------- capacity assignment (single block, deterministic) ----------------
__global__ void assign_k(const int* __restrict__ top_idx, const float* __restrict__ top_val,
                         int* __restrict__ toklist, float* __restrict__ wlist,
                         int* __restrict__ counts) {
    const int T = 256;
    const int CH = (2 * N_TOK) / T; // 32
    int t = threadIdx.x;
    for (int i = t; i < E_NUM * CAP; i += T) { toklist[i] = N_TOK; wlist[i] = 0.f; }
    __shared__ int cnt[T][E_NUM];
    int local[E_NUM];
#pragma unroll
    for (int e = 0; e < E_NUM; e++) local[e] = 0;
    for (int q = 0; q < CH; q++) {
        int j = t * CH + q;
        int slot = j >> 12;
        int tok  = j & 4095;
        int e = top_idx[tok * 2 + slot];
        local[e]++;
    }
#pragma unroll
    for (int e = 0; e < E_NUM; e++) cnt[t][e] = local[e];
    __syncthreads();
    if (t < E_NUM) {
        int run = 0;
        for (int i = 0; i < T; i++) { int c = cnt[i][t]; cnt[i][t] = run; run += c; }
        counts[t] = run < CAP ? run : CAP;
    }
    __syncthreads();
    int run[E_NUM];
#pragma unroll
    for (int e = 0; e < E_NUM; e++) run[e] = cnt[t][e];
    for (int q = 0; q < CH; q++) {
        int j = t * CH + q;
        int slot = j >> 12;
        int tok  = j & 4095;
        int e = top_idx[tok * 2 + slot];
        int rank = ++run[e];
        if (rank <= CAP) {
            toklist[e * CAP + rank - 1] = tok;
            wlist[e * CAP + rank - 1]   = top_val[tok * 2 + slot];
        }
    }
}

// ---------------- fused gate+up GEMM: h = silu(X Wg^T) * (X Wu^T) ----------------
__global__ __launch_bounds__(256)
void gateup_gemm(const us* __restrict__ A, const us* __restrict__ Wg,
                 const us* __restrict__ Wu, us* __restrict__ hbuf,
                 const int* __restrict__ toklist, const int* __restrict__ counts) {
    const int e  = blockIdx.z;
    const int m0 = blockIdx.y * 128;
    const int n0 = blockIdx.x * 128;
    if (m0 >= counts[e]) return;

    __shared__ us As[128 * 32];
    __shared__ us Gs[128 * 32];
    __shared__ us Us[128 * 32];

    const int t  = threadIdx.x;
    const int r0 = t >> 2;
    const int c8 = (t & 3) * 8;

    int tok0 = toklist[e * CAP + m0 + r0];
    int tok1 = toklist[e * CAP + m0 + r0 + 64];
    const us* aP0 = A + (size_t)tok0 * H_DIM + c8;
    const us* aP1 = A + (size_t)tok1 * H_DIM + c8;
    const us* gP0 = Wg + ((size_t)e * I_DIM + n0 + r0) * H_DIM + c8;
    const us* gP1 = gP0 + (size_t)64 * H_DIM;
    const us* uP0 = Wu + ((size_t)e * I_DIM + n0 + r0) * H_DIM + c8;
    const us* uP1 = uP0 + (size_t)64 * H_DIM;

    us* lA0 = As + t * 8; us* lA1 = lA0 + 64 * 32;
    us* lG0 = Gs + t * 8; us* lG1 = lG0 + 64 * 32;
    us* lU0 = Us + t * 8; us* lU1 = lU0 + 64 * 32;

    const int lane = t & 63;
    const int wave = t >> 6;
    const int wm   = (wave & 1) * 64;
    const int wn   = (wave >> 1) * 64;
    const int l15  = lane & 15;
    const int quad = lane >> 4;

    f32x4 ag[4][4], au[4][4];
#pragma unroll
    for (int i = 0; i < 4; i++)
#pragma unroll
        for (int j = 0; j < 4; j++) {
            ag[i][j] = (f32x4){0.f, 0.f, 0.f, 0.f};
            au[i][j] = (f32x4){0.f, 0.f, 0.f, 0.f};
        }

    for (int k = 0; k < H_DIM; k += 32) {
        gld_lds16(aP0, lA0);
        gld_lds16(aP1, lA1);
        gld_lds16(gP0, lG0);
        gld_lds16(gP1, lG1);
        gld_lds16(uP0, lU0);
        gld_lds16(uP1, lU1);
        aP0 += 32; aP1 += 32; gP0 += 32; gP1 += 32; uP0 += 32; uP1 += 32;
        __syncthreads();
        bf16x8 af[4], bg[4], bu[4];
#pragma unroll
        for (int i = 0; i < 4; i++)
            af[i] = *(const bf16x8*)(As + (wm + i * 16 + l15) * 32 + quad * 8);
#pragma unroll
        for (int j = 0; j < 4; j++) {
            bg[j] = *(const bf16x8*)(Gs + (wn + j * 16 + l15) * 32 + quad * 8);
            bu[j] = *(const bf16x8*)(Us + (wn + j * 16 + l15) * 32 + quad * 8);
        }
#pragma unroll
        for (int i = 0; i < 4; i++)
#pragma unroll
            for (int j = 0; j < 4; j++) {
                ag[i][j] = __builtin_amdgcn_mfma_f32_16x16x32_bf16(af[i], bg[j], ag[i][j], 0, 0, 0);
                au[i][j] = __builtin_amdgcn_mfma_f32_16x16x32_bf16(af[i], bu[j], au[i][j], 0, 0, 0);
            }
        __syncthreads();
    }

    // epilogue: C/D layout col = lane&15, row = quad*4 + reg;  h = silu(g)*u
#pragma unroll
    for (int i = 0; i < 4; i++) {
        int mb = m0 + wm + i * 16 + quad * 4;
#pragma unroll
        for (int r = 0; r < 4; r++) {
            size_t rowoff = ((size_t)e * CAP + mb + r) * I_DIM;
#pragma unroll
            for (int j = 0; j < 4; j++) {
                int n = n0 + wn + j * 16 + l15;
                float g = ag[i][j][r];
                float u = au[i][j][r];
                float h = (g / (1.f + __expf(-g))) * u;
                bf16 b = __float2bfloat16(h);
                hbuf[rowoff + n] = *(us*)&b;
            }
        }
    }
}

// ---------------- down GEMM: out[tok] += w * (h Wd^T) ----------------
__global__ __launch_bounds__(256)
void down_gemm(const us* __restrict__ A, const us* __restrict__ W,
               float* __restrict__ out,
               const int* __restrict__ toklist, const float* __restrict__ wlist,
               const int* __restrict__ counts) {
    const int e  = blockIdx.z;
    const int m0 = blockIdx.y * 128;
    const int n0 = blockIdx.x * 128;
    if (m0 >= counts[e]) return;

    __shared__ us As[128 * 32];
    __shared__ us Bs[128 * 32];

    const int t  = threadIdx.x;
    const int r0 = t >> 2;
    const int c8 = (t & 3) * 8;

    const us* aP0 = A + ((size_t)e * CAP + m0 + r0) * (size_t)I_DIM + c8;
    const us* aP1 = aP0 + (size_t)64 * I_DIM;
    const us* bP0 = W + ((size_t)e * H_DIM + n0 + r0) * (size_t)I_DIM + c8;
    const us* bP1 = bP0 + (size_t)64 * I_DIM;

    us* lA0 = As + t * 8; us* lA1 = lA0 + 64 * 32;
    us* lB0 = Bs + t * 8; us* lB1 = lB0 + 64 * 32;

    const int lane = t & 63;
    const int wave = t >> 6;
    const int wm   = (wave & 1) * 64;
    const int wn   = (wave >> 1) * 64;
    const int l15  = lane & 15;
    const int quad = lane >> 4;

    f32x4 acc[4][4];
#pragma unroll
    for (int i = 0; i < 4; i++)
#pragma unroll
        for (int j = 0; j < 4; j++) acc[i][j] = (f32x4){0.f, 0.f, 0.f, 0.f};

    for (int k = 0; k < I_DIM; k += 32) {
        gld_lds16(aP0, lA0);
        gld_lds16(aP1, lA1);
        gld_lds16(bP0, lB0);
        gld_lds16(bP1, lB1);
        aP0 += 32; aP1 += 32; bP0 += 32; bP1 += 32;
        __syncthreads();
        bf16x8 af[4], bfr[4];
#pragma unroll
        for (int i = 0; i < 4; i++)
            af[i] = *(const bf16x8*)(As + (wm + i * 16 + l15) * 32 + quad * 8);
#pragma unroll
        for (int j = 0; j < 4; j++)
            bfr[j] = *(const bf16x8*)(Bs + (wn + j * 16 + l15) * 32 + quad * 8);
#pragma unroll
        for (int i = 0; i < 4; i++)
#pragma unroll
            for (int j = 0; j < 4; j++)
                acc[i][j] = __builtin_amdgcn_mfma_f32_16x16x32_bf16(af[i], bfr[j], acc[i][j], 0, 0, 0);
        __syncthreads();
    }

#pragma unroll
    for (int i = 0; i < 4; i++) {
        int mb = m0 + wm + i * 16 + quad * 4;
#pragma unroll
        for (int r = 0; r < 4; r++) {
            int tok = toklist[e * CAP + mb + r];
            if (tok < N_TOK) {
                float wgt = wlist[e * CAP + mb + r];
                float* orow = out + (size_t)tok * H_DIM + n0 + wn + l15;
#pragma unroll
                for (int j = 0; j < 4; j++)
                    atomicAdd(orow + j * 16, wgt * acc[i][j][r]);
            }
        }
    }
}

extern "C" void kernel_launch(void* const* d_in, const int* in_sizes, int n_in,
                              void* d_out, int out_size, void* d_ws, size_t ws_size,
                              hipStream_t stream) {
    const float* x  = (const float*)d_in[0];
    const float* Wr = (const float*)d_in[1];
    const float* Wg = (const float*)d_in[2];
    const float* Wu = (const float*)d_in[3];
    const float* Wd = (const float*)d_in[4];
    float* out = (float*)d_out;

    char* p = (char*)d_ws;
    auto alloc = [&](size_t bytes) { char* r = p; p += (bytes + 255) & ~(size_t)255; return r; };
    us* xb   = (us*)alloc((size_t)(N_TOK + 1) * H_DIM * 2);
    us* Wgb  = (us*)alloc((size_t)E_NUM * I_DIM * H_DIM * 2);
    us* Wub  = (us*)alloc((size_t)E_NUM * I_DIM * H_DIM * 2);
    us* Wdb  = (us*)alloc((size_t)E_NUM * H_DIM * I_DIM * 2);
    us* hbuf = (us*)alloc((size_t)E_NUM * CAP * I_DIM * 2);
    float* top_val = (float*)alloc((size_t)N_TOK * 2 * 4);
    int*   top_idx = (int*)alloc((size_t)N_TOK * 2 * 4);
    int*   toklist = (int*)alloc((size_t)E_NUM * CAP * 4);
    float* wlist   = (float*)alloc((size_t)E_NUM * CAP * 4);
    int*   counts  = (int*)alloc((size_t)E_NUM * 4);

    hipMemsetAsync(out, 0, (size_t)N_TOK * H_DIM * 4, stream);
    hipMemsetAsync(xb + (size_t)N_TOK * H_DIM, 0, H_DIM * 2, stream);

    long nx = (long)N_TOK * H_DIM;
    long nw = (long)E_NUM * I_DIM * H_DIM;
    cvt4<<<dim3((unsigned)((nx / 4 + 255) / 256)), dim3(256), 0, stream>>>(x, xb, nx);
    cvt_w3<<<dim3((unsigned)((nw / 4 + 255) / 256), 1, 3), dim3(256), 0, stream>>>(
        Wg, Wu, Wd, Wgb, Wub, Wdb, nw);

    router_k<<<dim3(N_TOK / 4), dim3(256), 0, stream>>>(x, Wr, top_val, top_idx);
    assign_k<<<dim3(1), dim3(256), 0, stream>>>(top_idx, top_val, toklist, wlist, counts);

    dim3 g1(I_DIM / 128, CAP / 128, E_NUM);
    gateup_gemm<<<g1, dim3(256), 0, stream>>>(xb, Wgb, Wub, hbuf, toklist, counts);
    dim3 g2(H_DIM / 128, CAP / 128, E_NUM);
    down_gemm<<<g2, dim3(256), 0, stream>>>(hbuf, Wdb, out, toklist, wlist, counts);
}

// Round 3
// 739.623 us; speedup vs baseline: 1.0274x; 1.0274x over previous
//
#include <hip/hip_runtime.h>
#include <hip/hip_bf16.h>

#define N_TOK 4096
#define H_DIM 2048
#define I_DIM 1408
#define E_NUM 8
#define CAP   1280

typedef __hip_bfloat16 bf16;
typedef unsigned short us;
typedef __bf16 bf16x8 __attribute__((ext_vector_type(8)));
typedef float f32x4 __attribute__((ext_vector_type(4)));

__device__ inline void gld_lds16(const void* g, void* l) {
    __builtin_amdgcn_global_load_lds((const __attribute__((address_space(1))) void*)g,
                                     (__attribute__((address_space(3))) void*)l,
                                     16, 0, 0);
}

// ---------------- fp32 -> bf16 conversion, 8 elems/thread ----------------
__device__ inline void cvt_body8(const float* __restrict__ s, us* __restrict__ d, long i, long n) {
    if (i >= n) return;
    float4 v0 = *(const float4*)(s + i);
    float4 v1 = *(const float4*)(s + i + 4);
    union { us u[8]; uint4 q; } o;
    float f[8] = {v0.x, v0.y, v0.z, v0.w, v1.x, v1.y, v1.z, v1.w};
#pragma unroll
    for (int j = 0; j < 8; j++) {
        bf16 b = __float2bfloat16(f[j]);
        o.u[j] = *(us*)&b;
    }
    *(uint4*)(d + i) = o.q;
}

__global__ void cvt8(const float* __restrict__ s, us* __restrict__ d, long n) {
    long i = ((long)blockIdx.x * blockDim.x + threadIdx.x) * 8;
    cvt_body8(s, d, i, n);
}

__global__ void cvt_w3(const float* __restrict__ s0, const float* __restrict__ s1,
                       const float* __restrict__ s2, us* __restrict__ d0,
                       us* __restrict__ d1, us* __restrict__ d2, long n) {
    long i = ((long)blockIdx.x * blockDim.x + threadIdx.x) * 8;
    const float* s = blockIdx.z == 0 ? s0 : (blockIdx.z == 1 ? s1 : s2);
    us* d = blockIdx.z == 0 ? d0 : (blockIdx.z == 1 ? d1 : d2);
    cvt_body8(s, d, i, n);
}

// ---------------- router ----------------
__global__ void router_k(const float* __restrict__ x, const float* __restrict__ Wr,
                         float* __restrict__ top_val, int* __restrict__ top_idx) {
    int tok  = (blockIdx.x * blockDim.x + threadIdx.x) >> 6;
    int lane = threadIdx.x & 63;
    if (tok >= N_TOK) return;
    const float* xr = x + (size_t)tok * H_DIM;
    float acc[E_NUM];
#pragma unroll
    for (int e = 0; e < E_NUM; e++) acc[e] = 0.f;
    for (int h = lane; h < H_DIM; h += 64) {
        float xv = xr[h];
#pragma unroll
        for (int e = 0; e < E_NUM; e++) acc[e] += xv * Wr[e * H_DIM + h];
    }
#pragma unroll
    for (int e = 0; e < E_NUM; e++) {
#pragma unroll
        for (int off = 32; off > 0; off >>= 1) acc[e] += __shfl_xor(acc[e], off, 64);
    }
    if (lane == 0) {
        float mx = acc[0];
#pragma unroll
        for (int e = 1; e < E_NUM; e++) mx = fmaxf(mx, acc[e]);
        float p[E_NUM], s = 0.f;
#pragma unroll
        for (int e = 0; e < E_NUM; e++) { p[e] = __expf(acc[e] - mx); s += p[e]; }
        float inv = 1.f / s;
#pragma unroll
        for (int e = 0; e < E_NUM; e++) p[e] *= inv;
        int i0 = 0;
#pragma unroll
        for (int e = 1; e < E_NUM; e++) if (p[e] > p[i0]) i0 = e;
        int i1 = -1;
#pragma unroll
        for (int e = 0; e < E_NUM; e++) {
            if (e == i0) continue;
            if (i1 < 0 || p[e] > p[i1]) i1 = e;
        }
        top_idx[tok * 2]     = i0;
        top_idx[tok * 2 + 1] = i1;
        top_val[tok * 2]     = p[i0];
        top_val[tok * 2 + 1] = p[i1];
    }
}

// ---------------- capacity assignment ----------------
__global__ void assign_k(const int* __restrict__ top_idx, const float* __restrict__ top_val,
                         int* __restrict__ toklist, float* __restrict__ wlist,
                         int* __restrict__ counts) {
    const int T = 256;
    const int CH = (2 * N_TOK) / T; // 32
    int t = threadIdx.x;
    for (int i = t; i < E_NUM * CAP; i += T) { toklist[i] = N_TOK; wlist[i] = 0.f; }
    __shared__ int cnt[T][E_NUM];
    int local[E_NUM];
#pragma unroll
    for (int e = 0; e < E_NUM; e++) local[e] = 0;
    for (int q = 0; q < CH; q++) {
        int j = t * CH + q;
        int slot = j >> 12;
        int tok  = j & 4095;
        int e = top_idx[tok * 2 + slot];
        local[e]++;
    }
#pragma unroll
    for (int e = 0; e < E_NUM; e++) cnt[t][e] = local[e];
    __syncthreads();
    if (t < E_NUM) {
        int run = 0;
        for (int i = 0; i < T; i++) { int c = cnt[i][t]; cnt[i][t] = run; run += c; }
        counts[t] = run < CAP ? run : CAP;
    }
    __syncthreads();
    int run[E_NUM];
#pragma unroll
    for (int e = 0; e < E_NUM; e++) run[e] = cnt[t][e];
    for (int q = 0; q < CH; q++) {
        int j = t * CH + q;
        int slot = j >> 12;
        int tok  = j & 4095;
        int e = top_idx[tok * 2 + slot];
        int rank = ++run[e];
        if (rank <= CAP) {
            toklist[e * CAP + rank - 1] = tok;
            wlist[e * CAP + rank - 1]   = top_val[tok * 2 + slot];
        }
    }
}

// ---------------- gate & up as independent blocks in one dispatch ----------------
// z < 8: gbuf[e] = silu(X Wg[e]^T) ;  z >= 8: ubuf[e] = X Wu[e]^T
__global__ __launch_bounds__(256)
void gu_gemm(const us* __restrict__ A, const us* __restrict__ Wg,
             const us* __restrict__ Wu, us* __restrict__ gbuf, us* __restrict__ ubuf,
             const int* __restrict__ toklist, const int* __restrict__ counts) {
    const int z  = blockIdx.z;
    const int e  = z & 7;
    const int isU = z >> 3;
    const int m0 = blockIdx.y * 128;
    const int n0 = blockIdx.x * 128;
    if (m0 >= counts[e]) return;

    const us* W   = isU ? Wu : Wg;
    us* obuf      = isU ? ubuf : gbuf;

    __shared__ us As[128 * 32];
    __shared__ us Bs[128 * 32];

    const int t  = threadIdx.x;
    const int r0 = t >> 2;
    const int c8 = (t & 3) * 8;

    int tok0 = toklist[e * CAP + m0 + r0];
    int tok1 = toklist[e * CAP + m0 + r0 + 64];
    const us* aP0 = A + (size_t)tok0 * H_DIM + c8;
    const us* aP1 = A + (size_t)tok1 * H_DIM + c8;
    const us* bP0 = W + ((size_t)e * I_DIM + n0 + r0) * H_DIM + c8;
    const us* bP1 = bP0 + (size_t)64 * H_DIM;

    us* lA0 = As + t * 8; us* lA1 = lA0 + 64 * 32;
    us* lB0 = Bs + t * 8; us* lB1 = lB0 + 64 * 32;

    const int lane = t & 63;
    const int wave = t >> 6;
    const int wm   = (wave & 1) * 64;
    const int wn   = (wave >> 1) * 64;
    const int l15  = lane & 15;
    const int quad = lane >> 4;

    f32x4 acc[4][4];
#pragma unroll
    for (int i = 0; i < 4; i++)
#pragma unroll
        for (int j = 0; j < 4; j++) acc[i][j] = (f32x4){0.f, 0.f, 0.f, 0.f};

    for (int k = 0; k < H_DIM; k += 32) {
        gld_lds16(aP0, lA0);
        gld_lds16(aP1, lA1);
        gld_lds16(bP0, lB0);
        gld_lds16(bP1, lB1);
        aP0 += 32; aP1 += 32; bP0 += 32; bP1 += 32;
        __syncthreads();
        bf16x8 af[4], bfr[4];
#pragma unroll
        for (int i = 0; i < 4; i++)
            af[i] = *(const bf16x8*)(As + (wm + i * 16 + l15) * 32 + quad * 8);
#pragma unroll
        for (int j = 0; j < 4; j++)
            bfr[j] = *(const bf16x8*)(Bs + (wn + j * 16 + l15) * 32 + quad * 8);
#pragma unroll
        for (int i = 0; i < 4; i++)
#pragma unroll
            for (int j = 0; j < 4; j++)
                acc[i][j] = __builtin_amdgcn_mfma_f32_16x16x32_bf16(af[i], bfr[j], acc[i][j], 0, 0, 0);
        __syncthreads();
    }

#pragma unroll
    for (int i = 0; i < 4; i++) {
        int mb = m0 + wm + i * 16 + quad * 4;
#pragma unroll
        for (int r = 0; r < 4; r++) {
            size_t rowoff = ((size_t)e * CAP + mb + r) * I_DIM;
#pragma unroll
            for (int j = 0; j < 4; j++) {
                int n = n0 + wn + j * 16 + l15;
                float v = acc[i][j][r];
                if (!isU) v = v / (1.f + __expf(-v));   // silu on gate path
                bf16 b = __float2bfloat16(v);
                obuf[rowoff + n] = *(us*)&b;
            }
        }
    }
}

// ---------------- h = g * u (g already silu'd), bf16, 8/thread ----------------
__global__ void swiglu_mul(const us* __restrict__ g, const us* __restrict__ u,
                           us* __restrict__ h, long n) {
    long i = ((long)blockIdx.x * blockDim.x + threadIdx.x) * 8;
    if (i >= n) return;
    uint4 gq = *(const uint4*)(g + i);
    uint4 uq = *(const uint4*)(u + i);
    const us* gp = (const us*)&gq;
    const us* up = (const us*)&uq;
    union { us u[8]; uint4 q; } o;
#pragma unroll
    for (int j = 0; j < 8; j++) {
        float gv = __bfloat162float(*(const bf16*)&gp[j]);
        float uv = __bfloat162float(*(const bf16*)&up[j]);
        bf16 b = __float2bfloat16(gv * uv);
        o.u[j] = *(us*)&b;
    }
    *(uint4*)(h + i) = o.q;
}

// ---------------- down GEMM, split-K=2: out[tok] += w * (h Wd^T) ----------------
__global__ __launch_bounds__(256)
void down_gemm(const us* __restrict__ A, const us* __restrict__ W,
               float* __restrict__ out,
               const int* __restrict__ toklist, const float* __restrict__ wlist,
               const int* __restrict__ counts) {
    const int z  = blockIdx.z;
    const int e  = z & 7;
    const int k0 = (z >> 3) * (I_DIM / 2);   // 0 or 704
    const int m0 = blockIdx.y * 128;
    const int n0 = blockIdx.x * 128;
    if (m0 >= counts[e]) return;

    __shared__ us As[128 * 32];
    __shared__ us Bs[128 * 32];

    const int t  = threadIdx.x;
    const int r0 = t >> 2;
    const int c8 = (t & 3) * 8;

    const us* aP0 = A + ((size_t)e * CAP + m0 + r0) * (size_t)I_DIM + k0 + c8;
    const us* aP1 = aP0 + (size_t)64 * I_DIM;
    const us* bP0 = W + ((size_t)e * H_DIM + n0 + r0) * (size_t)I_DIM + k0 + c8;
    const us* bP1 = bP0 + (size_t)64 * I_DIM;

    us* lA0 = As + t * 8; us* lA1 = lA0 + 64 * 32;
    us* lB0 = Bs + t * 8; us* lB1 = lB0 + 64 * 32;

    const int lane = t & 63;
    const int wave = t >> 6;
    const int wm   = (wave & 1) * 64;
    const int wn   = (wave >> 1) * 64;
    const int l15  = lane & 15;
    const int quad = lane >> 4;

    f32x4 acc[4][4];
#pragma unroll
    for (int i = 0; i < 4; i++)
#pragma unroll
        for (int j = 0; j < 4; j++) acc[i][j] = (f32x4){0.f, 0.f, 0.f, 0.f};

    for (int k = 0; k < I_DIM / 2; k += 32) {
        gld_lds16(aP0, lA0);
        gld_lds16(aP1, lA1);
        gld_lds16(bP0, lB0);
        gld_lds16(bP1, lB1);
        aP0 += 32; aP1 += 32; bP0 += 32; bP1 += 32;
        __syncthreads();
        bf16x8 af[4], bfr[4];
#pragma unroll
        for (int i = 0; i < 4; i++)
            af[i] = *(const bf16x8*)(As + (wm + i * 16 + l15) * 32 + quad * 8);
#pragma unroll
        for (int j = 0; j < 4; j++)
            bfr[j] = *(const bf16x8*)(Bs + (wn + j * 16 + l15) * 32 + quad * 8);
#pragma unroll
        for (int i = 0; i < 4; i++)
#pragma unroll
            for (int j = 0; j < 4; j++)
                acc[i][j] = __builtin_amdgcn_mfma_f32_16x16x32_bf16(af[i], bfr[j], acc[i][j], 0, 0, 0);
        __syncthreads();
    }

#pragma unroll
    for (int i = 0; i < 4; i++) {
        int mb = m0 + wm + i * 16 + quad * 4;
#pragma unroll
        for (int r = 0; r < 4; r++) {
            int tok = toklist[e * CAP + mb + r];
            if (tok < N_TOK) {
                float wgt = wlist[e * CAP + mb + r];
                float* orow = out + (size_t)tok * H_DIM + n0 + wn + l15;
#pragma unroll
                for (int j = 0; j < 4; j++)
                    atomicAdd(orow + j * 16, wgt * acc[i][j][r]);
            }
        }
    }
}

extern "C" void kernel_launch(void* const* d_in, const int* in_sizes, int n_in,
                              void* d_out, int out_size, void* d_ws, size_t ws_size,
                              hipStream_t stream) {
    const float* x  = (const float*)d_in[0];
    const float* Wr = (const float*)d_in[1];
    const float* Wg = (const float*)d_in[2];
    const float* Wu = (const float*)d_in[3];
    const float* Wd = (const float*)d_in[4];
    float* out = (float*)d_out;

    char* p = (char*)d_ws;
    auto alloc = [&](size_t bytes) { char* r = p; p += (bytes + 255) & ~(size_t)255; return r; };
    us* xb   = (us*)alloc((size_t)(N_TOK + 1) * H_DIM * 2);
    us* Wgb  = (us*)alloc((size_t)E_NUM * I_DIM * H_DIM * 2);
    us* Wub  = (us*)alloc((size_t)E_NUM * I_DIM * H_DIM * 2);
    us* Wdb  = (us*)alloc((size_t)E_NUM * H_DIM * I_DIM * 2);
    us* gbuf = (us*)alloc((size_t)E_NUM * CAP * I_DIM * 2);
    us* ubuf = (us*)alloc((size_t)E_NUM * CAP * I_DIM * 2);
    us* hbuf = (us*)alloc((size_t)E_NUM * CAP * I_DIM * 2);
    float* top_val = (float*)alloc((size_t)N_TOK * 2 * 4);
    int*   top_idx = (int*)alloc((size_t)N_TOK * 2 * 4);
    int*   toklist = (int*)alloc((size_t)E_NUM * CAP * 4);
    float* wlist   = (float*)alloc((size_t)E_NUM * CAP * 4);
    int*   counts  = (int*)alloc((size_t)E_NUM * 4);

    hipMemsetAsync(out, 0, (size_t)N_TOK * H_DIM * 4, stream);
    hipMemsetAsync(xb + (size_t)N_TOK * H_DIM, 0, H_DIM * 2, stream);

    long nx = (long)N_TOK * H_DIM;
    long nw = (long)E_NUM * I_DIM * H_DIM;
    cvt8<<<dim3((unsigned)((nx / 8 + 255) / 256)), dim3(256), 0, stream>>>(x, xb, nx);
    cvt_w3<<<dim3((unsigned)((nw / 8 + 255) / 256), 1, 3), dim3(256), 0, stream>>>(
        Wg, Wu, Wd, Wgb, Wub, Wdb, nw);

    router_k<<<dim3(N_TOK / 4), dim3(256), 0, stream>>>(x, Wr, top_val, top_idx);
    assign_k<<<dim3(1), dim3(256), 0, stream>>>(top_idx, top_val, toklist, wlist, counts);

    dim3 g1(I_DIM / 128, CAP / 128, 16);   // 11 x 10 x 16 = 1760 blocks
    gu_gemm<<<g1, dim3(256), 0, stream>>>(xb, Wgb, Wub, gbuf, ubuf, toklist, counts);

    long nh = (long)E_NUM * CAP * I_DIM;
    swiglu_mul<<<dim3((unsigned)((nh / 8 + 255) / 256)), dim3(256), 0, stream>>>(gbuf, ubuf, hbuf, nh);

    dim3 g2(H_DIM / 128, CAP / 128, 16);   // 16 x 10 x 16 = 2560 blocks (split-K=2)
    down_gemm<<<g2, dim3(256), 0, stream>>>(hbuf, Wdb, out, toklist, wlist, counts);
}

// Round 4
// 688.568 us; speedup vs baseline: 1.1036x; 1.0741x over previous
//
#include <hip/hip_runtime.h>
#include <hip/hip_bf16.h>

#define N_TOK 4096
#define H_DIM 2048
#define I_DIM 1408
#define E_NUM 8
#define CAP   1280

typedef __hip_bfloat16 bf16;
typedef unsigned short us;
typedef __bf16 bf16x8 __attribute__((ext_vector_type(8)));
typedef float f32x4 __attribute__((ext_vector_type(4)));

__device__ inline void gld_lds16(const void* g, void* l) {
    __builtin_amdgcn_global_load_lds((const __attribute__((address_space(1))) void*)g,
                                     (__attribute__((address_space(3))) void*)l,
                                     16, 0, 0);
}

// ---------------- fp32 -> bf16 conversion, 8 elems/thread ----------------
__device__ inline void cvt_body8(const float* __restrict__ s, us* __restrict__ d, long i, long n) {
    if (i >= n) return;
    float4 v0 = *(const float4*)(s + i);
    float4 v1 = *(const float4*)(s + i + 4);
    union { us u[8]; uint4 q; } o;
    float f[8] = {v0.x, v0.y, v0.z, v0.w, v1.x, v1.y, v1.z, v1.w};
#pragma unroll
    for (int j = 0; j < 8; j++) {
        bf16 b = __float2bfloat16(f[j]);
        o.u[j] = *(us*)&b;
    }
    *(uint4*)(d + i) = o.q;
}

__global__ void cvt8(const float* __restrict__ s, us* __restrict__ d, long n) {
    long i = ((long)blockIdx.x * blockDim.x + threadIdx.x) * 8;
    cvt_body8(s, d, i, n);
}

__global__ void cvt_w3(const float* __restrict__ s0, const float* __restrict__ s1,
                       const float* __restrict__ s2, us* __restrict__ d0,
                       us* __restrict__ d1, us* __restrict__ d2, long n) {
    long i = ((long)blockIdx.x * blockDim.x + threadIdx.x) * 8;
    const float* s = blockIdx.z == 0 ? s0 : (blockIdx.z == 1 ? s1 : s2);
    us* d = blockIdx.z == 0 ? d0 : (blockIdx.z == 1 ? d1 : d2);
    cvt_body8(s, d, i, n);
}

// ---------------- router ----------------
__global__ void router_k(const float* __restrict__ x, const float* __restrict__ Wr,
                         float* __restrict__ top_val, int* __restrict__ top_idx) {
    int tok  = (blockIdx.x * blockDim.x + threadIdx.x) >> 6;
    int lane = threadIdx.x & 63;
    if (tok >= N_TOK) return;
    const float* xr = x + (size_t)tok * H_DIM;
    float acc[E_NUM];
#pragma unroll
    for (int e = 0; e < E_NUM; e++) acc[e] = 0.f;
    for (int h = lane; h < H_DIM; h += 64) {
        float xv = xr[h];
#pragma unroll
        for (int e = 0; e < E_NUM; e++) acc[e] += xv * Wr[e * H_DIM + h];
    }
#pragma unroll
    for (int e = 0; e < E_NUM; e++) {
#pragma unroll
        for (int off = 32; off > 0; off >>= 1) acc[e] += __shfl_xor(acc[e], off, 64);
    }
    if (lane == 0) {
        float mx = acc[0];
#pragma unroll
        for (int e = 1; e < E_NUM; e++) mx = fmaxf(mx, acc[e]);
        float p[E_NUM], s = 0.f;
#pragma unroll
        for (int e = 0; e < E_NUM; e++) { p[e] = __expf(acc[e] - mx); s += p[e]; }
        float inv = 1.f / s;
#pragma unroll
        for (int e = 0; e < E_NUM; e++) p[e] *= inv;
        int i0 = 0;
#pragma unroll
        for (int e = 1; e < E_NUM; e++) if (p[e] > p[i0]) i0 = e;
        int i1 = -1;
#pragma unroll
        for (int e = 0; e < E_NUM; e++) {
            if (e == i0) continue;
            if (i1 < 0 || p[e] > p[i1]) i1 = e;
        }
        top_idx[tok * 2]     = i0;
        top_idx[tok * 2 + 1] = i1;
        top_val[tok * 2]     = p[i0];
        top_val[tok * 2 + 1] = p[i1];
    }
}

// ---------------- capacity assignment ----------------
__global__ void assign_k(const int* __restrict__ top_idx, const float* __restrict__ top_val,
                         int* __restrict__ toklist, float* __restrict__ wlist,
                         int* __restrict__ counts) {
    const int T = 256;
    const int CH = (2 * N_TOK) / T; // 32
    int t = threadIdx.x;
    for (int i = t; i < E_NUM * CAP; i += T) { toklist[i] = N_TOK; wlist[i] = 0.f; }
    __shared__ int cnt[T][E_NUM];
    int local[E_NUM];
#pragma unroll
    for (int e = 0; e < E_NUM; e++) local[e] = 0;
    for (int q = 0; q < CH; q++) {
        int j = t * CH + q;
        int slot = j >> 12;
        int tok  = j & 4095;
        int e = top_idx[tok * 2 + slot];
        local[e]++;
    }
#pragma unroll
    for (int e = 0; e < E_NUM; e++) cnt[t][e] = local[e];
    __syncthreads();
    if (t < E_NUM) {
        int run = 0;
        for (int i = 0; i < T; i++) { int c = cnt[i][t]; cnt[i][t] = run; run += c; }
        counts[t] = run < CAP ? run : CAP;
    }
    __syncthreads();
    int run[E_NUM];
#pragma unroll
    for (int e = 0; e < E_NUM; e++) run[e] = cnt[t][e];
    for (int q = 0; q < CH; q++) {
        int j = t * CH + q;
        int slot = j >> 12;
        int tok  = j & 4095;
        int e = top_idx[tok * 2 + slot];
        int rank = ++run[e];
        if (rank <= CAP) {
            toklist[e * CAP + rank - 1] = tok;
            wlist[e * CAP + rank - 1]   = top_val[tok * 2 + slot];
        }
    }
}

// ---------------- gate & up GEMM, BK=64 (two BK=32 sub-buffers) ----------------
// z < 8: gbuf[e] = silu(X Wg[e]^T) ;  z >= 8: ubuf[e] = X Wu[e]^T
// grid: x = m-tiles (fastest -> consecutive blocks share the B weight tile in L2)
__global__ __launch_bounds__(256, 3)
void gu_gemm(const us* __restrict__ A, const us* __restrict__ Wg,
             const us* __restrict__ Wu, us* __restrict__ gbuf, us* __restrict__ ubuf,
             const int* __restrict__ toklist, const int* __restrict__ counts) {
    const int z  = blockIdx.z;
    const int e  = z & 7;
    const int isU = z >> 3;
    const int m0 = blockIdx.x * 128;
    const int n0 = blockIdx.y * 128;
    if (m0 >= counts[e]) return;

    const us* W = isU ? Wu : Wg;
    us* obuf    = isU ? ubuf : gbuf;

    __shared__ us As[128 * 64];   // two sub-buffers of [128][32]
    __shared__ us Bs[128 * 64];

    const int t  = threadIdx.x;
    const int r0 = t >> 2;          // 0..63
    const int c8 = (t & 3) * 8;     // 0/8/16/24

    int tok0 = toklist[e * CAP + m0 + r0];
    int tok1 = toklist[e * CAP + m0 + r0 + 64];
    const us* aP0 = A + (size_t)tok0 * H_DIM + c8;
    const us* aP1 = A + (size_t)tok1 * H_DIM + c8;
    const us* bP0 = W + ((size_t)e * I_DIM + n0 + r0) * H_DIM + c8;
    const us* bP1 = bP0 + (size_t)64 * H_DIM;

    us* lA0 = As + t * 8;  us* lA1 = lA0 + 64 * 32;   // sub0
    us* lB0 = Bs + t * 8;  us* lB1 = lB0 + 64 * 32;

    const int lane = t & 63;
    const int wave = t >> 6;
    const int wm   = (wave & 1) * 64;
    const int wn   = (wave >> 1) * 64;
    const int l15  = lane & 15;
    const int quad = lane >> 4;

    f32x4 acc[4][4];
#pragma unroll
    for (int i = 0; i < 4; i++)
#pragma unroll
        for (int j = 0; j < 4; j++) acc[i][j] = (f32x4){0.f, 0.f, 0.f, 0.f};

    for (int k = 0; k < H_DIM; k += 64) {
        gld_lds16(aP0,      lA0);
        gld_lds16(aP1,      lA1);
        gld_lds16(aP0 + 32, lA0 + 4096);
        gld_lds16(aP1 + 32, lA1 + 4096);
        gld_lds16(bP0,      lB0);
        gld_lds16(bP1,      lB1);
        gld_lds16(bP0 + 32, lB0 + 4096);
        gld_lds16(bP1 + 32, lB1 + 4096);
        aP0 += 64; aP1 += 64; bP0 += 64; bP1 += 64;
        __syncthreads();
#pragma unroll
        for (int kk = 0; kk < 2; kk++) {
            bf16x8 af[4], bfr[4];
#pragma unroll
            for (int i = 0; i < 4; i++)
                af[i] = *(const bf16x8*)(As + kk * 4096 + (wm + i * 16 + l15) * 32 + quad * 8);
#pragma unroll
            for (int j = 0; j < 4; j++)
                bfr[j] = *(const bf16x8*)(Bs + kk * 4096 + (wn + j * 16 + l15) * 32 + quad * 8);
#pragma unroll
            for (int i = 0; i < 4; i++)
#pragma unroll
                for (int j = 0; j < 4; j++)
                    acc[i][j] = __builtin_amdgcn_mfma_f32_16x16x32_bf16(af[i], bfr[j], acc[i][j], 0, 0, 0);
        }
        __syncthreads();
    }

#pragma unroll
    for (int i = 0; i < 4; i++) {
        int mb = m0 + wm + i * 16 + quad * 4;
#pragma unroll
        for (int r = 0; r < 4; r++) {
            size_t rowoff = ((size_t)e * CAP + mb + r) * I_DIM;
#pragma unroll
            for (int j = 0; j < 4; j++) {
                int n = n0 + wn + j * 16 + l15;
                float v = acc[i][j][r];
                if (!isU) v = v / (1.f + __expf(-v));   // silu on gate path
                bf16 b = __float2bfloat16(v);
                obuf[rowoff + n] = *(us*)&b;
            }
        }
    }
}

// ---------------- h = g * u ----------------
__global__ void swiglu_mul(const us* __restrict__ g, const us* __restrict__ u,
                           us* __restrict__ h, long n) {
    long i = ((long)blockIdx.x * blockDim.x + threadIdx.x) * 8;
    if (i >= n) return;
    uint4 gq = *(const uint4*)(g + i);
    uint4 uq = *(const uint4*)(u + i);
    const us* gp = (const us*)&gq;
    const us* up = (const us*)&uq;
    union { us u[8]; uint4 q; } o;
#pragma unroll
    for (int j = 0; j < 8; j++) {
        float gv = __bfloat162float(*(const bf16*)&gp[j]);
        float uv = __bfloat162float(*(const bf16*)&up[j]);
        bf16 b = __float2bfloat16(gv * uv);
        o.u[j] = *(us*)&b;
    }
    *(uint4*)(h + i) = o.q;
}

// ---------------- down GEMM, split-K=2, BK=64 ----------------
__global__ __launch_bounds__(256, 3)
void down_gemm(const us* __restrict__ A, const us* __restrict__ W,
               float* __restrict__ out,
               const int* __restrict__ toklist, const float* __restrict__ wlist,
               const int* __restrict__ counts) {
    const int z  = blockIdx.z;
    const int e  = z & 7;
    const int k0 = (z >> 3) * (I_DIM / 2);   // 0 or 704
    const int m0 = blockIdx.x * 128;
    const int n0 = blockIdx.y * 128;
    if (m0 >= counts[e]) return;

    __shared__ us As[128 * 64];
    __shared__ us Bs[128 * 64];

    const int t  = threadIdx.x;
    const int r0 = t >> 2;
    const int c8 = (t & 3) * 8;

    const us* aP0 = A + ((size_t)e * CAP + m0 + r0) * (size_t)I_DIM + k0 + c8;
    const us* aP1 = aP0 + (size_t)64 * I_DIM;
    const us* bP0 = W + ((size_t)e * H_DIM + n0 + r0) * (size_t)I_DIM + k0 + c8;
    const us* bP1 = bP0 + (size_t)64 * I_DIM;

    us* lA0 = As + t * 8;  us* lA1 = lA0 + 64 * 32;
    us* lB0 = Bs + t * 8;  us* lB1 = lB0 + 64 * 32;

    const int lane = t & 63;
    const int wave = t >> 6;
    const int wm   = (wave & 1) * 64;
    const int wn   = (wave >> 1) * 64;
    const int l15  = lane & 15;
    const int quad = lane >> 4;

    f32x4 acc[4][4];
#pragma unroll
    for (int i = 0; i < 4; i++)
#pragma unroll
        for (int j = 0; j < 4; j++) acc[i][j] = (f32x4){0.f, 0.f, 0.f, 0.f};

    for (int k = 0; k < I_DIM / 2; k += 64) {
        gld_lds16(aP0,      lA0);
        gld_lds16(aP1,      lA1);
        gld_lds16(aP0 + 32, lA0 + 4096);
        gld_lds16(aP1 + 32, lA1 + 4096);
        gld_lds16(bP0,      lB0);
        gld_lds16(bP1,      lB1);
        gld_lds16(bP0 + 32, lB0 + 4096);
        gld_lds16(bP1 + 32, lB1 + 4096);
        aP0 += 64; aP1 += 64; bP0 += 64; bP1 += 64;
        __syncthreads();
#pragma unroll
        for (int kk = 0; kk < 2; kk++) {
            bf16x8 af[4], bfr[4];
#pragma unroll
            for (int i = 0; i < 4; i++)
                af[i] = *(const bf16x8*)(As + kk * 4096 + (wm + i * 16 + l15) * 32 + quad * 8);
#pragma unroll
            for (int j = 0; j < 4; j++)
                bfr[j] = *(const bf16x8*)(Bs + kk * 4096 + (wn + j * 16 + l15) * 32 + quad * 8);
#pragma unroll
            for (int i = 0; i < 4; i++)
#pragma unroll
                for (int j = 0; j < 4; j++)
                    acc[i][j] = __builtin_amdgcn_mfma_f32_16x16x32_bf16(af[i], bfr[j], acc[i][j], 0, 0, 0);
        }
        __syncthreads();
    }

#pragma unroll
    for (int i = 0; i < 4; i++) {
        int mb = m0 + wm + i * 16 + quad * 4;
#pragma unroll
        for (int r = 0; r < 4; r++) {
            int tok = toklist[e * CAP + mb + r];
            if (tok < N_TOK) {
                float wgt = wlist[e * CAP + mb + r];
                float* orow = out + (size_t)tok * H_DIM + n0 + wn + l15;
#pragma unroll
                for (int j = 0; j < 4; j++)
                    atomicAdd(orow + j * 16, wgt * acc[i][j][r]);
            }
        }
    }
}

extern "C" void kernel_launch(void* const* d_in, const int* in_sizes, int n_in,
                              void* d_out, int out_size, void* d_ws, size_t ws_size,
                              hipStream_t stream) {
    const float* x  = (const float*)d_in[0];
    const float* Wr = (const float*)d_in[1];
    const float* Wg = (const float*)d_in[2];
    const float* Wu = (const float*)d_in[3];
    const float* Wd = (const float*)d_in[4];
    float* out = (float*)d_out;

    char* p = (char*)d_ws;
    auto alloc = [&](size_t bytes) { char* r = p; p += (bytes + 255) & ~(size_t)255; return r; };
    us* xb   = (us*)alloc((size_t)(N_TOK + 1) * H_DIM * 2);
    us* Wgb  = (us*)alloc((size_t)E_NUM * I_DIM * H_DIM * 2);
    us* Wub  = (us*)alloc((size_t)E_NUM * I_DIM * H_DIM * 2);
    us* Wdb  = (us*)alloc((size_t)E_NUM * H_DIM * I_DIM * 2);
    us* gbuf = (us*)alloc((size_t)E_NUM * CAP * I_DIM * 2);
    us* ubuf = (us*)alloc((size_t)E_NUM * CAP * I_DIM * 2);
    us* hbuf = (us*)alloc((size_t)E_NUM * CAP * I_DIM * 2);
    float* top_val = (float*)alloc((size_t)N_TOK * 2 * 4);
    int*   top_idx = (int*)alloc((size_t)N_TOK * 2 * 4);
    int*   toklist = (int*)alloc((size_t)E_NUM * CAP * 4);
    float* wlist   = (float*)alloc((size_t)E_NUM * CAP * 4);
    int*   counts  = (int*)alloc((size_t)E_NUM * 4);

    hipMemsetAsync(out, 0, (size_t)N_TOK * H_DIM * 4, stream);
    hipMemsetAsync(xb + (size_t)N_TOK * H_DIM, 0, H_DIM * 2, stream);

    long nx = (long)N_TOK * H_DIM;
    long nw = (long)E_NUM * I_DIM * H_DIM;
    cvt8<<<dim3((unsigned)((nx / 8 + 255) / 256)), dim3(256), 0, stream>>>(x, xb, nx);
    cvt_w3<<<dim3((unsigned)((nw / 8 + 255) / 256), 1, 3), dim3(256), 0, stream>>>(
        Wg, Wu, Wd, Wgb, Wub, Wdb, nw);

    router_k<<<dim3(N_TOK / 4), dim3(256), 0, stream>>>(x, Wr, top_val, top_idx);
    assign_k<<<dim3(1), dim3(256), 0, stream>>>(top_idx, top_val, toklist, wlist, counts);

    dim3 g1(CAP / 128, I_DIM / 128, 16);   // m fastest: 10 x 11 x 16
    gu_gemm<<<g1, dim3(256), 0, stream>>>(xb, Wgb, Wub, gbuf, ubuf, toklist, counts);

    long nh = (long)E_NUM * CAP * I_DIM;
    swiglu_mul<<<dim3((unsigned)((nh / 8 + 255) / 256)), dim3(256), 0, stream>>>(gbuf, ubuf, hbuf, nh);

    dim3 g2(CAP / 128, H_DIM / 128, 16);   // 10 x 16 x 16 (split-K=2)
    down_gemm<<<g2, dim3(256), 0, stream>>>(hbuf, Wdb, out, toklist, wlist, counts);
}